// Round 11
// baseline (117.436 us; speedup 1.0000x reference)
//
#include <hip/hip_runtime.h>
#include <hip/hip_bf16.h>

#define B_    64
#define DIM   640
#define TS    64
#define NT    10        // DIM/TS
#define TRI   205120    // DIM*(DIM+1)/2
#define EPS   1e-5f
#define SQEPS 3.1622776601683794e-3f
#define KCH   16        // uint4 chunks per img row (256 B row stride)
#define TILE_U4 1024    // uint4 per 64-row tile image (16 KB)
#define TILE_B  16384

typedef __attribute__((ext_vector_type(8)))  short bf16x8;
typedef __attribute__((ext_vector_type(16))) float f32x16;

__device__ inline unsigned pk_bf16(float a, float b) {
    __hip_bfloat162 h = __float22bfloat162_rn(float2{a, b});
    return *reinterpret_cast<unsigned*>(&h);
}
// sum of squares of the two bf16 values packed in pk (as fp32)
__device__ inline float bsq(unsigned pk) {
    union { unsigned u; float f; } a, c;
    a.u = pk << 16;
    c.u = pk & 0xffff0000u;
    return a.f * a.f + c.f * c.f;
}
__device__ inline float fsq(float x) { return __builtin_amdgcn_sqrtf(x); }

__device__ inline void gload_lds16(const void* g, void* l) {
    __builtin_amdgcn_global_load_lds(
        (const __attribute__((address_space(1))) unsigned*)g,
        (__attribute__((address_space(3))) unsigned*)l, 16, 0, 0);
}
// stage one 16 KB tile: 4 waves x 4 segs x 64 lanes x 16 B (coalesced)
__device__ inline void stage_tile16(const char* __restrict__ gt, char* lt,
                                    int wv, int lane) {
    #pragma unroll
    for (int it = 0; it < 4; ++it) {
        const int seg = (wv * 4 + it) * 1024;
        gload_lds16(gt + seg + lane * 16, lt + seg);
    }
}

// ---------------------------------------------------------------------------
// Persistent kernel: 640 blocks = (batch b, unit u in [0,10)).
//   Phase A: convert strip u -> bf16 img + dsq.          gate: ctrA[b]==10
//   Phase B: rowsums of strip u vs all 10 j-tiles.       gate: ctrB[b]==10
//   Phase C: centered triu tiles owned by (p,h)=u, packed store.
// Grid 640 <= co-residency capacity (>=3 blocks/CU) -> gates cannot deadlock.
// ---------------------------------------------------------------------------
__global__ __launch_bounds__(256, 4) void mega_kernel(
    const float* __restrict__ x, const float* __restrict__ temp,
    uint4* __restrict__ img, float* __restrict__ dsq,
    float* __restrict__ rowsum, unsigned* __restrict__ ctrA,
    unsigned* __restrict__ ctrB, float* __restrict__ out)
{
    __shared__ uint4 xj[2][TILE_U4];      // 32 KB (shared by phases B and C)
    __shared__ float dAll[DIM];           // dsq of whole batch
    __shared__ float e[DIM];              // centering vector (phase C)
    __shared__ float rpartw[2][TS];
    __shared__ float red4[4];

    const int raw = blockIdx.x;                       // 640 % 8 == 0
    const int bid = (raw & 7) * 80 + (raw >> 3);      // XCD-grouped
    const int b = bid / NT, u = bid % NT;
    const int t = threadIdx.x, wv = t >> 6, lane = t & 63;
    const int l31 = lane & 31, khalf = lane >> 5;
    const float tts = expf(temp[0]);

    // ---------------- Phase A: convert strip u -> img + dsq ---------------
    {
        const float4* src = (const float4*)x + (size_t)(b * DIM + u * TS) * 25;
        uint4* dst = img + (size_t)(b * NT + u) * TILE_U4;
        #pragma unroll
        for (int ff = 0; ff < 4; ++ff) {
            const int f = t + ff * 256;
            const int r = f >> 4, c = f & 15;
            uint4 p = {0u, 0u, 0u, 0u};
            float sq = 0.f;
            if (c <= 12) {
                float4 lo = src[(size_t)r * 25 + 2 * c];
                float4 hi = make_float4(0.f, 0.f, 0.f, 0.f);
                if (c < 12) hi = src[(size_t)r * 25 + 2 * c + 1];
                p.x = pk_bf16(lo.x, lo.y);
                p.y = pk_bf16(lo.z, lo.w);
                p.z = pk_bf16(hi.x, hi.y);
                p.w = pk_bf16(hi.z, hi.w);
                sq = bsq(p.x) + bsq(p.y) + bsq(p.z) + bsq(p.w);
            }
            dst[r * KCH + (c ^ (r & 15))] = p;
            // row sum-of-squares across the 16 lanes covering this row
            sq += __shfl_xor(sq, 1);
            sq += __shfl_xor(sq, 2);
            sq += __shfl_xor(sq, 4);
            sq += __shfl_xor(sq, 8);
            if (c == 0) dsq[b * DIM + u * TS + r] = sq;
        }
    }
    __syncthreads();   // drains stores (vmcnt 0) before the release
    if (t == 0)
        __hip_atomic_fetch_add(&ctrA[b], 1u, __ATOMIC_RELEASE,
                               __HIP_MEMORY_SCOPE_AGENT);

    // gate 1: whole batch converted
    if (t == 0) {
        while (__hip_atomic_load(&ctrA[b], __ATOMIC_ACQUIRE,
                                 __HIP_MEMORY_SCOPE_AGENT) < 10u)
            __builtin_amdgcn_s_sleep(2);
    }
    __syncthreads();

    // ---------------- Phase B: strip-u rowsums ----------------------------
    const char* base = (const char*)(img + (size_t)b * NT * TILE_U4);
    {
        stage_tile16(base, (char*)xj[0], wv, lane);
        for (int k = t; k < DIM; k += 256) dAll[k] = dsq[b * DIM + k];

        const int iq = wv & 1, jq = wv >> 1;
        const int irow = iq * 32 + l31;
        const uint4* own = img + (size_t)(b * NT + u) * TILE_U4;
        bf16x8 ifr[7];
        #pragma unroll
        for (int kk = 0; kk < 7; ++kk) {
            const int c = kk * 2 + khalf;
            ifr[kk] = *(const bf16x8*)&own[irow * KCH + (c ^ (irow & 15))];
        }
        const float dic = dsq[b * DIM + u * TS + irow];
        const int jr = jq * 32 + l31;
        __syncthreads();

        float rsum = 0.f;
        for (int jt = 0; jt < NT; ++jt) {
            if (jt + 1 < NT)
                stage_tile16(base + (size_t)(jt + 1) * TILE_B,
                             (char*)xj[(jt + 1) & 1], wv, lane);
            const uint4* buf = xj[jt & 1];
            bf16x8 jfr[7];
            #pragma unroll
            for (int kk = 0; kk < 7; ++kk) {
                const int c = kk * 2 + khalf;
                jfr[kk] = *(const bf16x8*)&buf[jr * KCH + (c ^ (jr & 15))];
            }
            f32x16 acc = {};
            #pragma unroll
            for (int kk = 0; kk < 7; ++kk)
                acc = __builtin_amdgcn_mfma_f32_32x32x16_bf16(jfr[kk], ifr[kk],
                                                              acc, 0, 0, 0);
            const bool dg = (jt == u);
            #pragma unroll
            for (int r = 0; r < 16; ++r) {
                const int rf = (r & 3) + 8 * (r >> 2) + 4 * khalf;
                const int jrow = jq * 32 + rf;
                const float dj = dAll[jt * TS + jrow];
                float uu = dj + dic - 2.f * acc[r];
                rsum += (dg && jrow == irow)
                      ? SQEPS : fsq(tts * fmaxf(uu, 0.f) + EPS);
            }
            __syncthreads();   // buffer consumed; next stage complete
        }

        rsum += __shfl_xor(rsum, 32);
        if (lane < 32) rpartw[jq][iq * 32 + lane] = rsum;
        __syncthreads();
        if (t < TS)
            rowsum[b * DIM + u * TS + t] = rpartw[0][t] + rpartw[1][t];
    }
    __syncthreads();   // drains rowsum stores before release
    if (t == 0)
        __hip_atomic_fetch_add(&ctrB[b], 1u, __ATOMIC_RELEASE,
                               __HIP_MEMORY_SCOPE_AGENT);

    // gate 2: whole batch's rowsums ready
    if (t == 0) {
        while (__hip_atomic_load(&ctrB[b], __ATOMIC_ACQUIRE,
                                 __HIP_MEMORY_SCOPE_AGENT) < 10u)
            __builtin_amdgcn_s_sleep(2);
    }
    __syncthreads();

    // ---------------- Phase C: centered triu tiles (owner (p,h)=u) --------
    {
        const int p = u >> 1, h = u & 1;
        const int wm = wv >> 1, wn = wv & 1;

        // stage first j-tile of strip p early (overlaps e[] build)
        const int jf0 = p + ((p ^ h) & 1);
        stage_tile16(base + (size_t)jf0 * TILE_B, (char*)xj[0], wv, lane);

        // e[k] = tm/2 - rowmean[k]  =>  centered = v + e[gi] + e[gj]
        float ps = 0.f;
        for (int k = t; k < DIM; k += 256) {
            float rs = rowsum[b * DIM + k];
            e[k] = rs;
            ps += rs;
        }
        ps += __shfl_xor(ps, 1);  ps += __shfl_xor(ps, 2);
        ps += __shfl_xor(ps, 4);  ps += __shfl_xor(ps, 8);
        ps += __shfl_xor(ps, 16); ps += __shfl_xor(ps, 32);
        if (lane == 0) red4[wv] = ps;
        __syncthreads();
        const float tm = (red4[0] + red4[1] + red4[2] + red4[3])
                       * (1.0f / ((float)DIM * (float)DIM));
        const float invD = 1.0f / (float)DIM;
        for (int k = t; k < DIM; k += 256)
            e[k] = 0.5f * tm - e[k] * invD;
        __syncthreads();

        const int arow = wm * 32 + l31;
        const int brow = wn * 32 + l31;

        #pragma unroll
        for (int si = 0; si < 2; ++si) {
            const int s = si ? (9 - p) : p;
            const int jf = s + ((s ^ h) & 1);
            if (jf >= NT) continue;            // block-uniform
            if (si == 1) {
                stage_tile16(base + (size_t)jf * TILE_B, (char*)xj[0],
                             wv, lane);
                __syncthreads();
            }
            const int i0 = s * TS;
            const uint4* ownt = img + (size_t)(b * NT + s) * TILE_U4;
            bf16x8 afr[7];
            #pragma unroll
            for (int kk = 0; kk < 7; ++kk) {
                const int c = kk * 2 + khalf;
                afr[kk] = *(const bf16x8*)&ownt[arow * KCH + (c ^ (arow & 15))];
            }

            for (int j = jf, idx = 0; j < NT; j += 2, ++idx) {
                if (j + 2 < NT)
                    stage_tile16(base + (size_t)(j + 2) * TILE_B,
                                 (char*)xj[(idx + 1) & 1], wv, lane);
                const uint4* buf = xj[idx & 1];
                bf16x8 bfr7[7];
                #pragma unroll
                for (int kk = 0; kk < 7; ++kk) {
                    const int c = kk * 2 + khalf;
                    bfr7[kk] = *(const bf16x8*)&buf[brow * KCH + (c ^ (brow & 15))];
                }
                f32x16 acc = {};
                #pragma unroll
                for (int kk = 0; kk < 7; ++kk)
                    acc = __builtin_amdgcn_mfma_f32_32x32x16_bf16(afr[kk], bfr7[kk],
                                                                  acc, 0, 0, 0);
                const int j0 = j * TS;
                const int gj = j0 + brow;
                const float djc = dAll[gj], ejc = e[gj];
                #pragma unroll
                for (int g = 0; g < 4; ++g) {
                    const int rbase = wm * 32 + 8 * g + 4 * khalf;
                    const float4 e4 = *(const float4*)&e[i0 + rbase];
                    const float4 d4 = *(const float4*)&dAll[i0 + rbase];
                    #pragma unroll
                    for (int q = 0; q < 4; ++q) {
                        const int r  = 4 * g + q;
                        const int gi = i0 + rbase + q;
                        float uu = ((const float*)&d4)[q] + djc - 2.f * acc[r];
                        float v = (gi == gj) ? SQEPS
                                             : fsq(tts * fmaxf(uu, 0.f) + EPS);
                        float cv = v + ((const float*)&e4)[q] + ejc;
                        const unsigned lo = (unsigned)min(gi, gj);
                        const unsigned hi2 = (unsigned)max(gi, gj);
                        unsigned idx32 = (unsigned)b * TRI + lo * DIM
                                       - ((lo * (lo - 1)) >> 1) - lo + hi2;
                        out[idx32] = cv;
                    }
                }
                __syncthreads();   // buffer consumed; next stage complete
            }
        }
    }
}

extern "C" void kernel_launch(void* const* d_in, const int* in_sizes, int n_in,
                              void* d_out, int out_size, void* d_ws, size_t ws_size,
                              hipStream_t stream)
{
    const float* x    = (const float*)d_in[0];
    const float* temp = (const float*)d_in[1];
    float* out = (float*)d_out;

    unsigned* ctrA  = (unsigned*)d_ws;                    // [64]
    unsigned* ctrB  = ctrA + 64;                          // [64]
    float* rowsum   = (float*)(ctrB + 64);                // [B_*DIM]
    float* dsq      = rowsum + B_ * DIM;                  // [B_*DIM]
    uint4* img      = (uint4*)(dsq + B_ * DIM);           // 10.5 MB

    hipMemsetAsync(ctrA, 0, 128 * sizeof(unsigned), stream);
    mega_kernel<<<B_ * NT, 256, 0, stream>>>(x, temp, img, dsq, rowsum,
                                             ctrA, ctrB, out);
}

// Round 12
// 108.391 us; speedup vs baseline: 1.0834x; 1.0834x over previous
//
#include <hip/hip_runtime.h>
#include <hip/hip_bf16.h>

#define B_    64
#define DIM   640
#define TS    64
#define NT    10        // DIM/TS
#define TRI   205120    // DIM*(DIM+1)/2
#define EPS   1e-5f
#define SQEPS 3.1622776601683794e-3f
#define KCH   16        // uint4 chunks per img row (256 B row stride)
#define TILE_U4 1024    // uint4 per 64-row tile image (16 KB)
#define TILE_B  16384

typedef __attribute__((ext_vector_type(8)))  short bf16x8;
typedef __attribute__((ext_vector_type(16))) float f32x16;

__device__ inline unsigned pk_bf16(float a, float b) {
    __hip_bfloat162 h = __float22bfloat162_rn(float2{a, b});
    return *reinterpret_cast<unsigned*>(&h);
}
// sum of squares of the two bf16 values packed in pk (as fp32)
__device__ inline float bsq(unsigned pk) {
    union { unsigned u; float f; } a, c;
    a.u = pk << 16;
    c.u = pk & 0xffff0000u;
    return a.f * a.f + c.f * c.f;
}
__device__ inline float fsq(float x) { return __builtin_amdgcn_sqrtf(x); }

__device__ inline void gload_lds16(const void* g, void* l) {
    __builtin_amdgcn_global_load_lds(
        (const __attribute__((address_space(1))) unsigned*)g,
        (__attribute__((address_space(3))) unsigned*)l, 16, 0, 0);
}
// stage one 16 KB tile: 4 waves x 4 segs x 64 lanes x 16 B (coalesced)
__device__ inline void stage_tile16(const char* __restrict__ gt, char* lt,
                                    int wv, int lane) {
    #pragma unroll
    for (int it = 0; it < 4; ++it) {
        const int seg = (wv * 4 + it) * 1024;
        gload_lds16(gt + seg + lane * 16, lt + seg);
    }
}

// Arrival gate: one release fence (L2 writeback) before arrival, RELAXED spin
// (no cache maintenance per iteration), one acquire fence (L2 inv) after.
__device__ inline void gate(unsigned* ctr, int t) {
    __syncthreads();             // all waves done (incl. vmcnt drain)
    if (t == 0) {
        __builtin_amdgcn_fence(__ATOMIC_RELEASE, "agent");
        __hip_atomic_fetch_add(ctr, 1u, __ATOMIC_RELAXED,
                               __HIP_MEMORY_SCOPE_AGENT);
        while (__hip_atomic_load(ctr, __ATOMIC_RELAXED,
                                 __HIP_MEMORY_SCOPE_AGENT) < 10u)
            __builtin_amdgcn_s_sleep(4);
        __builtin_amdgcn_fence(__ATOMIC_ACQUIRE, "agent");
    }
    __syncthreads();
}

// ---------------------------------------------------------------------------
// Persistent kernel: 640 blocks = (batch b, unit u in [0,10)).
//   Phase A: convert strip u -> bf16 img + dsq.          gate: ctrA[b]==10
//   Phase B: rowsums of strip u vs all 10 j-tiles.       gate: ctrB[b]==10
//   Phase C: centered triu tiles owned by (p,h)=u, packed store.
// Grid 640 <= co-residency capacity (4 blocks/CU) -> gates cannot deadlock.
// Batch's 10 blocks land on one XCD (bid/80 = XCD) -> L2-local handoff.
// ---------------------------------------------------------------------------
__global__ __launch_bounds__(256, 4) void mega_kernel(
    const float* __restrict__ x, const float* __restrict__ temp,
    uint4* __restrict__ img, float* __restrict__ dsq,
    float* __restrict__ rowsum, unsigned* __restrict__ ctrA,
    unsigned* __restrict__ ctrB, float* __restrict__ out)
{
    __shared__ uint4 xj[2][TILE_U4];      // 32 KB (shared by phases B and C)
    __shared__ float dAll[DIM];           // dsq of whole batch
    __shared__ float e[DIM];              // centering vector (phase C)
    __shared__ float rpartw[2][TS];
    __shared__ float red4[4];

    const int raw = blockIdx.x;                       // 640 % 8 == 0
    const int bid = (raw & 7) * 80 + (raw >> 3);      // XCD-grouped
    const int b = bid / NT, u = bid % NT;
    const int t = threadIdx.x, wv = t >> 6, lane = t & 63;
    const int l31 = lane & 31, khalf = lane >> 5;
    const float tts = expf(temp[0]);

    // ---------------- Phase A: convert strip u -> img + dsq ---------------
    {
        const float4* src = (const float4*)x + (size_t)(b * DIM + u * TS) * 25;
        uint4* dst = img + (size_t)(b * NT + u) * TILE_U4;
        #pragma unroll
        for (int ff = 0; ff < 4; ++ff) {
            const int f = t + ff * 256;
            const int r = f >> 4, c = f & 15;
            uint4 p = {0u, 0u, 0u, 0u};
            float sq = 0.f;
            if (c <= 12) {
                float4 lo = src[(size_t)r * 25 + 2 * c];
                float4 hi = make_float4(0.f, 0.f, 0.f, 0.f);
                if (c < 12) hi = src[(size_t)r * 25 + 2 * c + 1];
                p.x = pk_bf16(lo.x, lo.y);
                p.y = pk_bf16(lo.z, lo.w);
                p.z = pk_bf16(hi.x, hi.y);
                p.w = pk_bf16(hi.z, hi.w);
                sq = bsq(p.x) + bsq(p.y) + bsq(p.z) + bsq(p.w);
            }
            dst[r * KCH + (c ^ (r & 15))] = p;
            // row sum-of-squares across the 16 lanes covering this row
            sq += __shfl_xor(sq, 1);
            sq += __shfl_xor(sq, 2);
            sq += __shfl_xor(sq, 4);
            sq += __shfl_xor(sq, 8);
            if (c == 0) dsq[b * DIM + u * TS + r] = sq;
        }
    }
    gate(&ctrA[b], t);   // whole batch converted

    // ---------------- Phase B: strip-u rowsums ----------------------------
    const char* base = (const char*)(img + (size_t)b * NT * TILE_U4);
    {
        stage_tile16(base, (char*)xj[0], wv, lane);
        for (int k = t; k < DIM; k += 256) dAll[k] = dsq[b * DIM + k];

        const int iq = wv & 1, jq = wv >> 1;
        const int irow = iq * 32 + l31;
        const uint4* own = img + (size_t)(b * NT + u) * TILE_U4;
        bf16x8 ifr[7];
        #pragma unroll
        for (int kk = 0; kk < 7; ++kk) {
            const int c = kk * 2 + khalf;
            ifr[kk] = *(const bf16x8*)&own[irow * KCH + (c ^ (irow & 15))];
        }
        const float dic = dsq[b * DIM + u * TS + irow];
        const int jr = jq * 32 + l31;
        __syncthreads();

        float rsum = 0.f;
        for (int jt = 0; jt < NT; ++jt) {
            if (jt + 1 < NT)
                stage_tile16(base + (size_t)(jt + 1) * TILE_B,
                             (char*)xj[(jt + 1) & 1], wv, lane);
            const uint4* buf = xj[jt & 1];
            bf16x8 jfr[7];
            #pragma unroll
            for (int kk = 0; kk < 7; ++kk) {
                const int c = kk * 2 + khalf;
                jfr[kk] = *(const bf16x8*)&buf[jr * KCH + (c ^ (jr & 15))];
            }
            f32x16 acc = {};
            #pragma unroll
            for (int kk = 0; kk < 7; ++kk)
                acc = __builtin_amdgcn_mfma_f32_32x32x16_bf16(jfr[kk], ifr[kk],
                                                              acc, 0, 0, 0);
            const bool dg = (jt == u);
            #pragma unroll
            for (int r = 0; r < 16; ++r) {
                const int rf = (r & 3) + 8 * (r >> 2) + 4 * khalf;
                const int jrow = jq * 32 + rf;
                const float dj = dAll[jt * TS + jrow];
                float uu = dj + dic - 2.f * acc[r];
                rsum += (dg && jrow == irow)
                      ? SQEPS : fsq(tts * fmaxf(uu, 0.f) + EPS);
            }
            __syncthreads();   // buffer consumed; next stage complete
        }

        rsum += __shfl_xor(rsum, 32);
        if (lane < 32) rpartw[jq][iq * 32 + lane] = rsum;
        __syncthreads();
        if (t < TS)
            rowsum[b * DIM + u * TS + t] = rpartw[0][t] + rpartw[1][t];
    }
    gate(&ctrB[b], t);   // whole batch's rowsums ready

    // ---------------- Phase C: centered triu tiles (owner (p,h)=u) --------
    {
        const int p = u >> 1, h = u & 1;
        const int wm = wv >> 1, wn = wv & 1;

        // stage first j-tile of strip p early (overlaps e[] build)
        const int jf0 = p + ((p ^ h) & 1);
        stage_tile16(base + (size_t)jf0 * TILE_B, (char*)xj[0], wv, lane);

        // e[k] = tm/2 - rowmean[k]  =>  centered = v + e[gi] + e[gj]
        float ps = 0.f;
        for (int k = t; k < DIM; k += 256) {
            float rs = rowsum[b * DIM + k];
            e[k] = rs;
            ps += rs;
        }
        ps += __shfl_xor(ps, 1);  ps += __shfl_xor(ps, 2);
        ps += __shfl_xor(ps, 4);  ps += __shfl_xor(ps, 8);
        ps += __shfl_xor(ps, 16); ps += __shfl_xor(ps, 32);
        if (lane == 0) red4[wv] = ps;
        __syncthreads();
        const float tm = (red4[0] + red4[1] + red4[2] + red4[3])
                       * (1.0f / ((float)DIM * (float)DIM));
        const float invD = 1.0f / (float)DIM;
        for (int k = t; k < DIM; k += 256)
            e[k] = 0.5f * tm - e[k] * invD;
        __syncthreads();

        const int arow = wm * 32 + l31;
        const int brow = wn * 32 + l31;

        #pragma unroll
        for (int si = 0; si < 2; ++si) {
            const int s = si ? (9 - p) : p;
            const int jf = s + ((s ^ h) & 1);
            if (jf >= NT) continue;            // block-uniform
            if (si == 1) {
                stage_tile16(base + (size_t)jf * TILE_B, (char*)xj[0],
                             wv, lane);
                __syncthreads();
            }
            const int i0 = s * TS;
            const uint4* ownt = img + (size_t)(b * NT + s) * TILE_U4;
            bf16x8 afr[7];
            #pragma unroll
            for (int kk = 0; kk < 7; ++kk) {
                const int c = kk * 2 + khalf;
                afr[kk] = *(const bf16x8*)&ownt[arow * KCH + (c ^ (arow & 15))];
            }

            for (int j = jf, idx = 0; j < NT; j += 2, ++idx) {
                if (j + 2 < NT)
                    stage_tile16(base + (size_t)(j + 2) * TILE_B,
                                 (char*)xj[(idx + 1) & 1], wv, lane);
                const uint4* buf = xj[idx & 1];
                bf16x8 bfr7[7];
                #pragma unroll
                for (int kk = 0; kk < 7; ++kk) {
                    const int c = kk * 2 + khalf;
                    bfr7[kk] = *(const bf16x8*)&buf[brow * KCH + (c ^ (brow & 15))];
                }
                f32x16 acc = {};
                #pragma unroll
                for (int kk = 0; kk < 7; ++kk)
                    acc = __builtin_amdgcn_mfma_f32_32x32x16_bf16(afr[kk], bfr7[kk],
                                                                  acc, 0, 0, 0);
                const int j0 = j * TS;
                const int gj = j0 + brow;
                const float djc = dAll[gj], ejc = e[gj];
                #pragma unroll
                for (int g = 0; g < 4; ++g) {
                    const int rbase = wm * 32 + 8 * g + 4 * khalf;
                    const float4 e4 = *(const float4*)&e[i0 + rbase];
                    const float4 d4 = *(const float4*)&dAll[i0 + rbase];
                    #pragma unroll
                    for (int q = 0; q < 4; ++q) {
                        const int r  = 4 * g + q;
                        const int gi = i0 + rbase + q;
                        float uu = ((const float*)&d4)[q] + djc - 2.f * acc[r];
                        float v = (gi == gj) ? SQEPS
                                             : fsq(tts * fmaxf(uu, 0.f) + EPS);
                        float cv = v + ((const float*)&e4)[q] + ejc;
                        const unsigned lo = (unsigned)min(gi, gj);
                        const unsigned hi2 = (unsigned)max(gi, gj);
                        unsigned idx32 = (unsigned)b * TRI + lo * DIM
                                       - ((lo * (lo - 1)) >> 1) - lo + hi2;
                        out[idx32] = cv;
                    }
                }
                __syncthreads();   // buffer consumed; next stage complete
            }
        }
    }
}

extern "C" void kernel_launch(void* const* d_in, const int* in_sizes, int n_in,
                              void* d_out, int out_size, void* d_ws, size_t ws_size,
                              hipStream_t stream)
{
    const float* x    = (const float*)d_in[0];
    const float* temp = (const float*)d_in[1];
    float* out = (float*)d_out;

    unsigned* ctrA  = (unsigned*)d_ws;                    // [64]
    unsigned* ctrB  = ctrA + 64;                          // [64]
    float* rowsum   = (float*)(ctrB + 64);                // [B_*DIM]
    float* dsq      = rowsum + B_ * DIM;                  // [B_*DIM]
    uint4* img      = (uint4*)(dsq + B_ * DIM);           // 10.5 MB

    hipMemsetAsync(ctrA, 0, 128 * sizeof(unsigned), stream);
    mega_kernel<<<B_ * NT, 256, 0, stream>>>(x, temp, img, dsq, rowsum,
                                             ctrA, ctrB, out);
}

// Round 13
// 47.443 us; speedup vs baseline: 2.4753x; 2.2846x over previous
//
#include <hip/hip_runtime.h>
#include <hip/hip_bf16.h>

#define B_    64
#define DIM   640
#define TS    64
#define NT    10        // DIM/TS
#define TRI   205120    // DIM*(DIM+1)/2
#define EPS   1e-5f
#define SQEPS 3.1622776601683794e-3f
#define KCH   16        // uint4 chunks per img row (256 B row stride)
#define TILE_U4 1024    // uint4 per 64-row tile image (16 KB)
#define TILE_B  16384

typedef __attribute__((ext_vector_type(8)))  short bf16x8;
typedef __attribute__((ext_vector_type(16))) float f32x16;

__device__ inline unsigned pk_bf16(float a, float b) {
    __hip_bfloat162 h = __float22bfloat162_rn(float2{a, b});
    return *reinterpret_cast<unsigned*>(&h);
}
// sum of squares of the two bf16 values packed in pk (as fp32)
__device__ inline float bsq(unsigned pk) {
    union { unsigned u; float f; } a, c;
    a.u = pk << 16;
    c.u = pk & 0xffff0000u;
    return a.f * a.f + c.f * c.f;
}
__device__ inline float fsq(float x) { return __builtin_amdgcn_sqrtf(x); }

__device__ inline void gload_lds16(const void* g, void* l) {
    __builtin_amdgcn_global_load_lds(
        (const __attribute__((address_space(1))) unsigned*)g,
        (__attribute__((address_space(3))) unsigned*)l, 16, 0, 0);
}
// stage one 16 KB tile: 4 waves x 4 segs x 64 lanes x 16 B (coalesced)
__device__ inline void stage_tile16(const char* __restrict__ gt, char* lt,
                                    int wv, int lane) {
    #pragma unroll
    for (int it = 0; it < 4; ++it) {
        const int seg = (wv * 4 + it) * 1024;
        gload_lds16(gt + seg + lane * 16, lt + seg);
    }
}

// ---------------------------------------------------------------------------
// K0 prep: per (b,s) convert 64x100 fp32 strip -> swizzled bf16 img tile
// (K zero-padded) + per-row sum of squares, single pass over x.
// ---------------------------------------------------------------------------
__global__ __launch_bounds__(256) void prep_kernel(
    const float* __restrict__ x, uint4* __restrict__ img,
    float* __restrict__ dsq)
{
    const int blk = blockIdx.x;                 // b*NT + s
    const int b = blk / NT, s = blk % NT;
    const int t = threadIdx.x;
    const float4* src = (const float4*)x + (size_t)(b * DIM + s * TS) * 25;
    uint4* dst = img + (size_t)blk * TILE_U4;

    #pragma unroll
    for (int ff = 0; ff < 4; ++ff) {
        const int f = t + ff * 256;
        const int r = f >> 4, c = f & 15;
        uint4 p = {0u, 0u, 0u, 0u};
        float sq = 0.f;
        if (c <= 12) {
            float4 lo = src[(size_t)r * 25 + 2 * c];
            float4 hi = make_float4(0.f, 0.f, 0.f, 0.f);
            if (c < 12) hi = src[(size_t)r * 25 + 2 * c + 1];
            p.x = pk_bf16(lo.x, lo.y);
            p.y = pk_bf16(lo.z, lo.w);
            p.z = pk_bf16(hi.x, hi.y);
            p.w = pk_bf16(hi.z, hi.w);
            sq = bsq(p.x) + bsq(p.y) + bsq(p.z) + bsq(p.w);
        }
        dst[r * KCH + (c ^ (r & 15))] = p;
        // row sum-of-squares across the 16 lanes covering this row
        sq += __shfl_xor(sq, 1);
        sq += __shfl_xor(sq, 2);
        sq += __shfl_xor(sq, 4);
        sq += __shfl_xor(sq, 8);
        if (c == 0) dsq[b * DIM + s * TS + r] = sq;
    }
}

// ---------------------------------------------------------------------------
// K1: one block per (b, strip s, j-parity h).  Partial dcov row sums for rows
// [s*64, s*64+64) over j-tiles of parity h.  A-frags direct from L2 (no LDS
// staging); j-tiles double-buffered via global_load_lds.
// ---------------------------------------------------------------------------
__global__ __launch_bounds__(256, 4) void strip_kernel(
    const uint4* __restrict__ img, const float* __restrict__ dsq,
    const float* __restrict__ temp, float* __restrict__ rowsum_part)
{
    __shared__ uint4 xj[2][TILE_U4];      // 32 KB
    __shared__ float dAll[DIM];
    __shared__ float rpartw[2][TS];

    const int raw = blockIdx.x;                       // 1280 % 8 == 0
    const int bid = (raw & 7) * 160 + (raw >> 3);     // XCD-grouped
    const int b = bid / 20, rem = bid % 20;
    const int s = rem >> 1, h = rem & 1;
    const int t = threadIdx.x, wv = t >> 6, lane = t & 63;
    const int l31 = lane & 31, khalf = lane >> 5;
    const int iq = wv & 1, jq = wv >> 1;
    const float tts = expf(temp[0]);
    const char* base = (const char*)(img + (size_t)b * NT * TILE_U4);

    stage_tile16(base + (size_t)h * TILE_B, (char*)xj[0], wv, lane);
    for (int k = t; k < DIM; k += 256) dAll[k] = dsq[b * DIM + k];

    // own-strip A-fragments straight from global (L2-hot, one-time)
    const int irow = iq * 32 + l31;
    const uint4* own = img + (size_t)(b * NT + s) * TILE_U4;
    bf16x8 ifr[7];
    #pragma unroll
    for (int kk = 0; kk < 7; ++kk) {
        const int c = kk * 2 + khalf;
        ifr[kk] = *(const bf16x8*)&own[irow * KCH + (c ^ (irow & 15))];
    }
    const int jr = jq * 32 + l31;
    __syncthreads();
    const float dic = dAll[s * TS + irow];

    float rsum = 0.f;
    #pragma unroll
    for (int jj = 0; jj < 5; ++jj) {
        const int jt = h + 2 * jj;
        if (jj < 4)
            stage_tile16(base + (size_t)(jt + 2) * TILE_B,
                         (char*)xj[(jj + 1) & 1], wv, lane);
        const uint4* buf = xj[jj & 1];
        bf16x8 jfr[7];
        #pragma unroll
        for (int kk = 0; kk < 7; ++kk) {
            const int c = kk * 2 + khalf;
            jfr[kk] = *(const bf16x8*)&buf[jr * KCH + (c ^ (jr & 15))];
        }
        f32x16 acc = {};
        #pragma unroll
        for (int kk = 0; kk < 7; ++kk)
            acc = __builtin_amdgcn_mfma_f32_32x32x16_bf16(jfr[kk], ifr[kk],
                                                          acc, 0, 0, 0);
        const bool dg = (jt == s);
        #pragma unroll
        for (int r = 0; r < 16; ++r) {
            const int rf = (r & 3) + 8 * (r >> 2) + 4 * khalf;
            const int jrow = jq * 32 + rf;
            const float dj = dAll[jt * TS + jrow];
            float u = dj + dic - 2.f * acc[r];
            rsum += (dg && jrow == irow)
                  ? SQEPS : fsq(tts * fmaxf(u, 0.f) + EPS);
        }
        __syncthreads();   // buffer consumed; next stage complete
    }

    rsum += __shfl_xor(rsum, 32);
    if (lane < 32) rpartw[jq][iq * 32 + lane] = rsum;
    __syncthreads();
    if (t < TS)
        rowsum_part[h * (B_ * DIM) + b * DIM + s * TS + t]
            = rpartw[0][t] + rpartw[1][t];
}

// ---------------------------------------------------------------------------
// K2: one block per (b, strip-pair p, j-parity h).  Owns triu tiles of strips
// {p, 9-p} with j-parity h.  A-frags direct from L2; e[]-centering; counted
// vmcnt(16) barrier lets output stores stay in flight across tiles (T4).
// ---------------------------------------------------------------------------
__global__ __launch_bounds__(256, 4) void write_kernel(
    const uint4* __restrict__ img, const float* __restrict__ dsq,
    const float* __restrict__ temp, const float* __restrict__ rowsum_part,
    float* __restrict__ out)
{
    __shared__ uint4 xjb[2][TILE_U4];     // 32 KB
    __shared__ float e[DIM];
    __shared__ float dAll[DIM];
    __shared__ float red4[4];

    const int raw = blockIdx.x;                       // 640 % 8 == 0
    const int bid = (raw & 7) * 80 + (raw >> 3);      // XCD-grouped
    const int b = bid / 10, rem = bid % 10;
    const int p = rem >> 1, h = rem & 1;
    const int t = threadIdx.x, wv = t >> 6, lane = t & 63;
    const int l31 = lane & 31, khalf = lane >> 5;
    const int wm = wv >> 1, wn = wv & 1;
    const float tts = expf(temp[0]);
    const char* base = (const char*)(img + (size_t)b * NT * TILE_U4);
    const float* r0 = rowsum_part + b * DIM;
    const float* r1 = rowsum_part + (B_ * DIM) + b * DIM;

    // stage first j-tile of strip p early (overlaps e[] build)
    const int jf0 = p + ((p ^ h) & 1);
    stage_tile16(base + (size_t)jf0 * TILE_B, (char*)xjb[0], wv, lane);

    // e[k] = tm/2 - rowmean[k]  =>  centered = v + e[gi] + e[gj]
    float ps = 0.f;
    for (int k = t; k < DIM; k += 256) {
        float rs = r0[k] + r1[k];
        e[k] = rs;
        dAll[k] = dsq[b * DIM + k];
        ps += rs;
    }
    ps += __shfl_xor(ps, 1);  ps += __shfl_xor(ps, 2);
    ps += __shfl_xor(ps, 4);  ps += __shfl_xor(ps, 8);
    ps += __shfl_xor(ps, 16); ps += __shfl_xor(ps, 32);
    if (lane == 0) red4[wv] = ps;
    __syncthreads();
    const float tm = (red4[0] + red4[1] + red4[2] + red4[3])
                   * (1.0f / ((float)DIM * (float)DIM));
    const float invD = 1.0f / (float)DIM;
    for (int k = t; k < DIM; k += 256)
        e[k] = 0.5f * tm - e[k] * invD;
    __syncthreads();   // full drain: first stage + LDS ready

    const int arow = wm * 32 + l31;
    const int brow = wn * 32 + l31;

    #pragma unroll
    for (int si = 0; si < 2; ++si) {
        const int s = si ? (9 - p) : p;
        const int jf = s + ((s ^ h) & 1);
        if (jf >= NT) continue;
        if (si == 1) {   // stage first j tile of second strip
            stage_tile16(base + (size_t)jf * TILE_B, (char*)xjb[0], wv, lane);
            __syncthreads();
        }
        const int i0 = s * TS;
        // A-fragments straight from global (L2-hot, once per strip)
        const uint4* ownt = img + (size_t)(b * NT + s) * TILE_U4;
        bf16x8 afr[7];
        #pragma unroll
        for (int kk = 0; kk < 7; ++kk) {
            const int c = kk * 2 + khalf;
            afr[kk] = *(const bf16x8*)&ownt[arow * KCH + (c ^ (arow & 15))];
        }

        for (int j = jf, idx = 0; j < NT; j += 2, ++idx) {
            if (j + 2 < NT)
                stage_tile16(base + (size_t)(j + 2) * TILE_B,
                             (char*)xjb[(idx + 1) & 1], wv, lane);
            const uint4* buf = xjb[idx & 1];
            bf16x8 bfr7[7];
            #pragma unroll
            for (int kk = 0; kk < 7; ++kk) {
                const int c = kk * 2 + khalf;
                bfr7[kk] = *(const bf16x8*)&buf[brow * KCH + (c ^ (brow & 15))];
            }
            f32x16 acc = {};
            #pragma unroll
            for (int kk = 0; kk < 7; ++kk)
                acc = __builtin_amdgcn_mfma_f32_32x32x16_bf16(afr[kk], bfr7[kk],
                                                              acc, 0, 0, 0);
            const int j0 = j * TS;
            const int gj = j0 + brow;
            const float djc = dAll[gj], ejc = e[gj];
            #pragma unroll
            for (int g = 0; g < 4; ++g) {
                const int rbase = wm * 32 + 8 * g + 4 * khalf;
                const float4 e4 = *(const float4*)&e[i0 + rbase];
                const float4 d4 = *(const float4*)&dAll[i0 + rbase];
                #pragma unroll
                for (int q = 0; q < 4; ++q) {
                    const int r  = 4 * g + q;
                    const int gi = i0 + rbase + q;
                    float u = ((const float*)&d4)[q] + djc - 2.f * acc[r];
                    float v = (gi == gj) ? SQEPS
                                         : fsq(tts * fmaxf(u, 0.f) + EPS);
                    float cv = v + ((const float*)&e4)[q] + ejc;
                    // branch-free symmetric store (diag tiles: mirrored lanes
                    // write the same value to the same address -- benign)
                    const unsigned lo = (unsigned)min(gi, gj);
                    const unsigned hi2 = (unsigned)max(gi, gj);
                    unsigned idx32 = (unsigned)b * TRI + lo * DIM
                                   - ((lo * (lo - 1)) >> 1) - lo + hi2;
                    out[idx32] = cv;
                }
            }
            // T4 counted barrier: vmcnt retires in issue order, so <=16
            // outstanding guarantees the (older) 4 stage ops are complete
            // while this tile's 16 stores may remain in flight.
            asm volatile("s_waitcnt vmcnt(16)" ::: "memory");
            __builtin_amdgcn_sched_barrier(0);
            __builtin_amdgcn_s_barrier();
        }
    }
}

extern "C" void kernel_launch(void* const* d_in, const int* in_sizes, int n_in,
                              void* d_out, int out_size, void* d_ws, size_t ws_size,
                              hipStream_t stream)
{
    const float* x    = (const float*)d_in[0];
    const float* temp = (const float*)d_in[1];
    float* out         = (float*)d_out;

    float* rowsum_part = (float*)d_ws;                    // [2][B_*DIM]
    float* dsq         = rowsum_part + 2 * B_ * DIM;      // [B_*DIM]
    uint4* img         = (uint4*)(dsq + B_ * DIM);        // 10.5 MB

    prep_kernel <<<B_ * NT,     256, 0, stream>>>(x, img, dsq);
    strip_kernel<<<2 * B_ * NT, 256, 0, stream>>>(img, dsq, temp, rowsum_part);
    write_kernel<<<B_ * NT,     256, 0, stream>>>(img, dsq, temp, rowsum_part, out);
}